// Round 12
// baseline (235.831 us; speedup 1.0000x reference)
//
#include <hip/hip_runtime.h>

#define IN_DIM 128
#define HID 64
#define STAGE_CAP 12288

// ---------------- bucket histogram: per-block partials, no global atomics/memset ----------------
__global__ __launch_bounds__(256) void k_bin_count(const int* __restrict__ dst, int E,
                                                   int* __restrict__ hist2d) {
    __shared__ int h[256];
    int tid = threadIdx.x;
    h[tid] = 0;
    __syncthreads();
    int base = blockIdx.x * 4096;
    int end = min(base + 4096, E);
    for (int i = base + tid; i < end; i += 256) atomicAdd(&h[dst[i] >> 8], 1);
    __syncthreads();
    hist2d[blockIdx.x * 256 + tid] = h[tid];
}

// ---------------- bucket exclusive scan (sums 2D partials) + gcur=0 + sentinels ----------------
__global__ __launch_bounds__(256) void k_bucket_scan(const int* __restrict__ hist2d, int eblk,
                                                     int* __restrict__ bbase,
                                                     int* __restrict__ gcur,
                                                     int* __restrict__ row_start, int N, int E) {
    int tid = threadIdx.x, lane = tid & 63, wid = tid >> 6;
    int v = 0;
    for (int k = 0; k < eblk; ++k) v += hist2d[k * 256 + tid];
    int orig = v;
    for (int off = 1; off < 64; off <<= 1) {
        int t = __shfl_up(v, off);
        if (lane >= off) v += t;
    }
    __shared__ int ws[4];
    if (lane == 63) ws[wid] = v;
    __syncthreads();
    int woff = 0;
    for (int w = 0; w < wid; ++w) woff += ws[w];
    bbase[tid] = woff + v - orig;
    gcur[tid] = 0;
    if (tid == 0) {
        bbase[256] = E;
        row_start[N] = E;
    }
}

// ---------------- CSR build, phase A: bucket-chunked scatter (N < 65536) ----------------
__global__ __launch_bounds__(512) void k_bin_scatter(const int* __restrict__ src,
                                                     const int* __restrict__ dst, int E,
                                                     const int* __restrict__ bbase,
                                                     int* __restrict__ gcur,
                                                     unsigned* __restrict__ ebuf) {
    __shared__ int hist[256];
    __shared__ int gbase[256];
    int tid = threadIdx.x;
    for (int i = tid; i < 256; i += 512) hist[i] = 0;
    __syncthreads();
    int base = blockIdx.x * 4096;
    int pk[8], bkt[8], rnk[8];
#pragma unroll
    for (int i = 0; i < 8; ++i) {
        int e = base + tid + i * 512;
        if (e < E) {
            int s = src[e];
            int d = dst[e];
            bkt[i] = d >> 8;
            pk[i] = ((d & 255) << 16) | s;
            rnk[i] = atomicAdd(&hist[bkt[i]], 1);
        } else {
            bkt[i] = -1;
        }
    }
    __syncthreads();
    for (int b = tid; b < 256; b += 512) {
        int c = hist[b];
        if (c > 0) gbase[b] = bbase[b] + atomicAdd(&gcur[b], c);
    }
    __syncthreads();
#pragma unroll
    for (int i = 0; i < 8; ++i) {
        if (bkt[i] >= 0) ebuf[gbase[bkt[i]] + rnk[i]] = (unsigned)pk[i];
    }
}

// ---------------- CSR build, phase B (fused): degree+scan -> row_start, dis ; LDS sort ----------------
__global__ __launch_bounds__(512) void k_bin_sort(const unsigned* __restrict__ ebuf,
                                                  const int* __restrict__ bbase, int N, int E,
                                                  int* __restrict__ row_start,
                                                  float* __restrict__ dis,
                                                  int* __restrict__ csr_src) {
    __shared__ int ldeg[256];
    __shared__ int loff[256];
    __shared__ int lcur[256];
    __shared__ int wsum[8];
    __shared__ unsigned short stage[STAGE_CAP];
    int tid = threadIdx.x;
    int node0 = blockIdx.x << 8;
    int nnode = min(256, N - node0);
    for (int i = tid; i < 256; i += 512) {
        ldeg[i] = 0;
        lcur[i] = 0;
    }
    __syncthreads();
    int bstart = bbase[blockIdx.x];
    int bend = bbase[blockIdx.x + 1];
    int cnt = bend - bstart;
    for (int i = tid; i < cnt; i += 512) {
        unsigned u = ebuf[bstart + i];
        atomicAdd(&ldeg[(u >> 16) & 255], 1);
    }
    __syncthreads();
    int lane = tid & 63, wid = tid >> 6;
    int v = 0, orig = 0;
    if (tid < 256) {
        orig = ldeg[tid];
        v = orig;
    }
    for (int off = 1; off < 64; off <<= 1) {
        int t = __shfl_up(v, off);
        if (lane >= off) v += t;
    }
    if (lane == 63) wsum[wid] = v;
    __syncthreads();
    if (tid < 256) {
        int woff = 0;
        for (int w = 0; w < wid && w < 4; ++w) woff += wsum[w];
        int excl = woff + v - orig;
        loff[tid] = excl;
        if (tid < nnode) {
            row_start[node0 + tid] = bstart + excl;
            dis[node0 + tid] = rsqrtf((float)(orig + 1));
        }
    }
    __syncthreads();
    if (cnt <= STAGE_CAP) {
        for (int i = tid; i < cnt; i += 512) {
            unsigned u = ebuf[bstart + i];
            int dlo = (u >> 16) & 255;
            int pos = loff[dlo] + atomicAdd(&lcur[dlo], 1);
            stage[pos] = (unsigned short)(u & 0xFFFF);
        }
        __syncthreads();
        for (int i = tid; i < cnt; i += 512) csr_src[bstart + i] = (int)stage[i];
    } else {
        for (int i = tid; i < cnt; i += 512) {
            unsigned u = ebuf[bstart + i];
            int dlo = (u >> 16) & 255;
            int pos = bstart + loff[dlo] + atomicAdd(&lcur[dlo], 1);
            csr_src[pos] = (int)(u & 0xFFFF);
        }
    }
}

// ---------------- K-chunked tiled GEMM: out[r][c] = dis[r]*sum_k X[r][k]*W[k][c] ----------------
template <int K>
__global__ __launch_bounds__(256) void k_gemm_scale(const float* __restrict__ X,
                                                    const float* __restrict__ W,
                                                    const float* __restrict__ dis, int N,
                                                    float* __restrict__ out) {
    constexpr int CH = 64;
    constexpr int CHP = CH + 4;
    constexpr int KC = K / 4;
    __shared__ float Xs[64 * CHP];
    __shared__ float Ws[CH * 64];
    int tid = threadIdx.x;
    int row0 = blockIdx.x * 64;
    int cg = tid & 15;
    int rg = tid >> 4;
    float acc[4][4] = {};
    const float4* Wg = (const float4*)W;
    const float4* Xg = (const float4*)X;
    float4* Ws4 = (float4*)Ws;

#pragma unroll
    for (int k0 = 0; k0 < K; k0 += CH) {
        if (k0) __syncthreads();
        for (int i = tid; i < CH * 16; i += 256) Ws4[i] = Wg[k0 * 16 + i];
        for (int c = tid; c < 64 * 16; c += 256) {
            int r = c >> 4, k4 = c & 15;
            int row = row0 + r;
            float4 vv = make_float4(0.f, 0.f, 0.f, 0.f);
            if (row < N) vv = Xg[(size_t)row * KC + (k0 >> 2) + k4];
            *(float4*)&Xs[r * CHP + k4 * 4] = vv;
        }
        __syncthreads();
#pragma unroll 2
        for (int k = 0; k < CH; k += 4) {
            float4 w0 = *(float4*)&Ws[(k + 0) * 64 + cg * 4];
            float4 w1 = *(float4*)&Ws[(k + 1) * 64 + cg * 4];
            float4 w2 = *(float4*)&Ws[(k + 2) * 64 + cg * 4];
            float4 w3 = *(float4*)&Ws[(k + 3) * 64 + cg * 4];
#pragma unroll
            for (int i = 0; i < 4; ++i) {
                float4 xv = *(float4*)&Xs[(rg * 4 + i) * CHP + k];
                acc[i][0] += xv.x * w0.x + xv.y * w1.x + xv.z * w2.x + xv.w * w3.x;
                acc[i][1] += xv.x * w0.y + xv.y * w1.y + xv.z * w2.y + xv.w * w3.y;
                acc[i][2] += xv.x * w0.z + xv.y * w1.z + xv.z * w2.z + xv.w * w3.z;
                acc[i][3] += xv.x * w0.w + xv.y * w1.w + xv.z * w2.w + xv.w * w3.w;
            }
        }
    }
#pragma unroll
    for (int i = 0; i < 4; ++i) {
        int row = row0 + rg * 4 + i;
        if (row < N) {
            float s = dis[row];
            *(float4*)&out[(size_t)row * 64 + cg * 4] =
                make_float4(acc[i][0] * s, acc[i][1] * s, acc[i][2] * s, acc[i][3] * s);
        }
    }
}

// ---------------- sliced gather-aggregate: 4 column-slices x XCD-affine passes ----------------
// pass = (blockIdx&7)>>1 covers columns [pass*16, pass*16+16) -> slice = 3.2MB, fits XCD L2.
// block = 1024 thr = 16 waves = 16 nodes. lane = g*4 + t (16 subgroups of 4 lanes).
// out[node][pass-slice] = relu(dis[node]*(Hs[node] + sum Hs[src]) + bias)  [Hs pre-scaled by dis]
__global__ __launch_bounds__(1024) void k_agg_slice(const float* __restrict__ Hs,
                                                    const int* __restrict__ row_start,
                                                    const int* __restrict__ csr_src,
                                                    const float* __restrict__ dis,
                                                    const float* __restrict__ bias, int N,
                                                    float* __restrict__ out) {
    const float4* Hs4 = (const float4*)Hs;
    int blk = blockIdx.x;
    int slot = blk & 7;
    int pass = slot >> 1;
    int idx = ((blk >> 3) << 1) | (slot & 1);
    int wave = threadIdx.x >> 6, lane = threadIdx.x & 63;
    int node = idx * 16 + wave;
    if (node >= N) return;
    int t = lane & 3, g = lane >> 2;
    int cbase = pass * 4;  // float4 offset within the 16-float4 row
    float4 a = make_float4(0.f, 0.f, 0.f, 0.f);
    if (g == 0) a = Hs4[(size_t)node * 16 + cbase + t];  // self loop
    int e0 = row_start[node], e1 = row_start[node + 1];
    for (int eb = e0; eb < e1; eb += 64) {
        int cnt = min(64, e1 - eb);
        int sv = (eb + lane < e1) ? csr_src[eb + lane] : 0;
        for (int jb = 0; jb < cnt; jb += 32) {
            int i0 = jb + g, i1 = jb + 16 + g;
            int s0 = __shfl(sv, i0 < cnt ? i0 : 0);
            int s1 = __shfl(sv, i1 < cnt ? i1 : 0);
            float4 z0 = Hs4[(size_t)s0 * 16 + cbase + t];
            float4 z1 = Hs4[(size_t)s1 * 16 + cbase + t];
            if (i0 < cnt) {
                a.x += z0.x; a.y += z0.y; a.z += z0.z; a.w += z0.w;
            }
            if (i1 < cnt) {
                a.x += z1.x; a.y += z1.y; a.z += z1.z; a.w += z1.w;
            }
        }
    }
#pragma unroll
    for (int off = 4; off < 64; off <<= 1) {
        a.x += __shfl_xor(a.x, off);
        a.y += __shfl_xor(a.y, off);
        a.z += __shfl_xor(a.z, off);
        a.w += __shfl_xor(a.w, off);
    }
    float sc = dis[node];
    float4 b = ((const float4*)bias)[cbase + t];
    float4 v;
    v.x = fmaxf(a.x * sc + b.x, 0.f);
    v.y = fmaxf(a.y * sc + b.y, 0.f);
    v.z = fmaxf(a.z * sc + b.z, 0.f);
    v.w = fmaxf(a.w * sc + b.w, 0.f);
    if (g == 0) ((float4*)out)[(size_t)node * 16 + cbase + t] = v;
}

// ---------------- head: logits = h @ Wl + bl  ([N,64]x[64,2]) ----------------
__global__ __launch_bounds__(256) void k_head(const float* __restrict__ H,
                                              const float* __restrict__ Wl,
                                              const float* __restrict__ bl, int N,
                                              float* __restrict__ out) {
    int wave = threadIdx.x >> 6, lane = threadIdx.x & 63;
    int node = blockIdx.x * 4 + wave;
    if (node >= N) return;
    float h = H[(size_t)node * HID + lane];
    float a0 = h * Wl[lane * 2 + 0];
    float a1 = h * Wl[lane * 2 + 1];
    for (int off = 32; off; off >>= 1) {
        a0 += __shfl_down(a0, off);
        a1 += __shfl_down(a1, off);
    }
    if (lane == 0) {
        out[node * 2 + 0] = a0 + bl[0];
        out[node * 2 + 1] = a1 + bl[1];
    }
}

extern "C" void kernel_launch(void* const* d_in, const int* in_sizes, int n_in,
                              void* d_out, int out_size, void* d_ws, size_t ws_size,
                              hipStream_t stream) {
    const float* x  = (const float*)d_in[0];
    const int*   ei = (const int*)d_in[1];
    const float* W1 = (const float*)d_in[2];
    const float* b1 = (const float*)d_in[3];
    const float* W2 = (const float*)d_in[4];
    const float* b2 = (const float*)d_in[5];
    const float* Wl = (const float*)d_in[6];
    const float* bl = (const float*)d_in[7];

    const int N = in_sizes[0] / IN_DIM;   // 50000 (< 65536 required by packing)
    const int E = in_sizes[1] / 2;        // 800000
    const int* src = ei;
    const int* dst = ei + E;

    char* ws = (char*)d_ws;
    size_t off = 0;
    auto alloc = [&](size_t bytes) -> void* {
        void* p = ws + off;
        off = (off + bytes + 255) & ~(size_t)255;
        return p;
    };
    const int eblk = (E + 4095) / 4096;  // 196
    const int nb = (N + 255) / 256;      // 196
    int*   hist2d    = (int*)alloc((size_t)eblk * 256 * 4);
    int*   bbase     = (int*)alloc(257 * 4);
    int*   gcur      = (int*)alloc(256 * 4);
    int*   row_start = (int*)alloc(((size_t)N + 1) * 4);
    float* dis       = (float*)alloc((size_t)N * 4);
    int*   csr_src   = (int*)alloc((size_t)E * 4);
    float* bufA      = (float*)alloc((size_t)N * HID * 4);
    float* bufB      = (float*)alloc((size_t)N * HID * 4);
    unsigned* ebuf   = (unsigned*)bufA;  // alias: consumed by bin_sort before gemm1 writes bufA

    k_bin_count<<<eblk, 256, 0, stream>>>(dst, E, hist2d);
    k_bucket_scan<<<1, 256, 0, stream>>>(hist2d, eblk, bbase, gcur, row_start, N, E);
    k_bin_scatter<<<eblk, 512, 0, stream>>>(src, dst, E, bbase, gcur, ebuf);
    k_bin_sort<<<nb, 512, 0, stream>>>(ebuf, bbase, N, E, row_start, dis, csr_src);

    const int gblk = (N + 63) / 64;              // 782
    const int nodeBlocks = (N + 15) / 16;        // 3125
    const int aggGrid = ((nodeBlocks + 1) / 2) * 8;  // 12504
    const int hblk = (N + 3) / 4;                // 12500

    k_gemm_scale<IN_DIM><<<gblk, 256, 0, stream>>>(x, W1, dis, N, bufA);
    k_agg_slice<<<aggGrid, 1024, 0, stream>>>(bufA, row_start, csr_src, dis, b1, N, bufB);
    k_gemm_scale<HID><<<gblk, 256, 0, stream>>>(bufB, W2, dis, N, bufA);
    k_agg_slice<<<aggGrid, 1024, 0, stream>>>(bufA, row_start, csr_src, dis, b2, N, bufB);
    k_head<<<hblk, 256, 0, stream>>>(bufB, Wl, bl, N, (float*)d_out);
}